// Round 9
// baseline (376.119 us; speedup 1.0000x reference)
//
#include <hip/hip_runtime.h>
#include <hip/hip_bf16.h>

// GraphVertEdgeNet on MI355X. B=64, N=64, VF=32, EF=16, DV=DE=128, LN=4.
// e stored bf16 in ws (64MB) in TRANSPOSED layout e_t[b][j][i][c].
// Round-9: edge_inner restructured to 4 cols/block (1024 blocks), two
// 2-col pairs double-buffered through a 70KB LDS: pair1's HBM loads are
// issued while pair0 computes; pair0's write-back overlaps pair1's MFMA.
// EVGEN (BN(v)@evW via MFMA) runs ONCE per 4 cols (was per 2). 2 blocks/CU
// (8 waves) -- trading occupancy for explicit intra-block overlap, since
// the measured regime is phase-serialization (HBM 22% busy, MFMA 8%,
// VALU 28%; nothing saturated). Other kernels: round-8 proven forms.

typedef __bf16 bf16_t;
typedef __bf16 bf16x8 __attribute__((ext_vector_type(8)));
typedef __bf16 bf16x4 __attribute__((ext_vector_type(4)));
typedef __bf16 bf16x2 __attribute__((ext_vector_type(2)));
typedef float f32x4 __attribute__((ext_vector_type(4)));

__device__ __forceinline__ void bar_lgkm() {
  asm volatile("s_waitcnt lgkmcnt(0)\n\ts_barrier" ::: "memory");
}

__device__ __forceinline__ unsigned pack2(float a, float b) {
  bf16_t ba = (bf16_t)a, bb = (bf16_t)b;
  unsigned short ua, ub;
  __builtin_memcpy(&ua, &ba, 2);
  __builtin_memcpy(&ub, &bb, 2);
  return (unsigned)ua | ((unsigned)ub << 16);
}
__device__ __forceinline__ float blo(unsigned u) {
  unsigned v = u << 16; float f; __builtin_memcpy(&f, &v, 4); return f;
}
__device__ __forceinline__ float bhi(unsigned u) {
  unsigned v = u & 0xffff0000u; float f; __builtin_memcpy(&f, &v, 4); return f;
}

// ---------------- prep: input BN (v0), transposes, packed weights, zero stats ----------
__global__ __launch_bounds__(256) void k_prep(const float* __restrict__ vin,
    const float* __restrict__ g, const float* __restrict__ bt,
    const float* __restrict__ eW, const float* __restrict__ inn_vW,
    const float* __restrict__ g1_vW, const float* __restrict__ inn_evW,
    float* __restrict__ v0, bf16_t* __restrict__ Wt, float* __restrict__ stats,
    unsigned* __restrict__ vWp, unsigned* __restrict__ g1_vWp,
    unsigned* __restrict__ evWp, bf16_t* __restrict__ evWtB) {
  const int blk = blockIdx.x, tid = threadIdx.x;
  if (blk < 8) {
    int ch = blk * 256 + tid;
    float s = 0.f, s2 = 0.f;
    for (int b = 0; b < 64; ++b) { float x = vin[b * 2048 + ch]; s += x; s2 += x * x; }
    float mu = s * (1.f / 64.f);
    float var = s2 * (1.f / 64.f) - mu * mu;
    float sc = rsqrtf(var + 1e-5f) * g[ch];
    float bb = bt[ch];
    for (int b = 0; b < 64; ++b) {
      float x = vin[b * 2048 + ch];
      v0[b * 2048 + ch] = (x - mu) * sc + bb;
    }
  } else if (blk < 264) {
    int idx = (blk - 8) * 256 + tid;
    int l = idx >> 14, r = idx & 16383, n = r >> 7, k = r & 127;
    Wt[idx] = (bf16_t)eW[(l << 14) + (k << 7) + n];
  } else if (blk == 264) {
    for (int i = tid; i < 512; i += 256) stats[i] = 0.f;
  } else if (blk < 521) {
    int idx = (blk - 265) * 256 + tid;
    int l = idx >> 14, r = idx & 16383;
    int k8 = r >> 9, c = (r >> 2) & 127, j = r & 3;
    int ka = k8 * 8 + j * 2;
    vWp[idx] = pack2(inn_vW[(l << 15) + ka * 128 + c],
                     inn_vW[(l << 15) + (ka + 1) * 128 + c]);
  } else if (blk < 561) {
    int idx = (blk - 521) * 256 + tid;
    int k8 = idx >> 9, c = (idx >> 2) & 127, j = idx & 3;
    int ka = k8 * 8 + j * 2;
    g1_vWp[idx] = pack2(g1_vW[ka * 128 + c], g1_vW[(ka + 1) * 128 + c]);
  } else if (blk < 689) {
    int idx = (blk - 561) * 256 + tid;
    int l = idx >> 13, r = idx & 8191;
    int k8 = r >> 9, c = (r >> 2) & 127, j = r & 3;
    int ka = k8 * 8 + j * 2;
    evWp[idx] = pack2(inn_evW[(l << 14) + ka * 128 + c],
                      inn_evW[(l << 14) + (ka + 1) * 128 + c]);
  } else {
    int idx = (blk - 689) * 256 + tid;
    int l = idx >> 14, r = idx & 16383, n = r >> 7, k = r & 127;
    evWtB[idx] = (bf16_t)inn_evW[(l << 14) + (k << 7) + n];
  }
}

// ------------- ev = v_in @ W + bias : [4096,32]@[32,128] (g1 only). 8 rows/blk -------------
template <int K>
__global__ __launch_bounds__(256) void k_ev(const float* __restrict__ v_in,
    const float* __restrict__ W, const float* __restrict__ bias,
    float* __restrict__ out) {
  __shared__ float rows_s[8][K];
  const int r0 = blockIdx.x * 8;
  const int tid = threadIdx.x;
  const int c = tid & 127, h = tid >> 7;
  for (int idx = tid; idx < 8 * K; idx += 256) {
    int rr = idx / K, kk = idx % K;
    rows_s[rr][kk] = v_in[(r0 + rr) * K + kk];
  }
  __syncthreads();
  float acc[4];
  const float bv = bias[c];
#pragma unroll
  for (int r = 0; r < 4; ++r) acc[r] = bv;
  for (int k4 = 0; k4 < K; k4 += 4) {
    float w0 = W[(k4 + 0) * 128 + c], w1 = W[(k4 + 1) * 128 + c];
    float w2 = W[(k4 + 2) * 128 + c], w3 = W[(k4 + 3) * 128 + c];
#pragma unroll
    for (int r = 0; r < 4; ++r) {
      float4 x = *(const float4*)&rows_s[h * 4 + r][k4];
      acc[r] += x.x * w0 + x.y * w1 + x.z * w2 + x.w * w3;
    }
  }
#pragma unroll
  for (int r = 0; r < 4; ++r) out[(r0 + h * 4 + r) * 128 + c] = acc[r];
}

// ------------- g1 edge pass + fused g1-v + layer-0 ev (round-7/8 form, unchanged) ------
__global__ __launch_bounds__(256) void k_edge_g1(const float* __restrict__ e0,
    const float* __restrict__ eW, const float* __restrict__ eb,
    const float* __restrict__ evA, bf16_t* __restrict__ e_ws,
    const float* __restrict__ v0, const uint4* __restrict__ g1_vWp,
    const float* __restrict__ vb, const uint4* __restrict__ evW0p,
    const float* __restrict__ evb, float* __restrict__ v,
    float* __restrict__ evB) {
  __shared__ bf16_t A0s[2][64][40];
  __shared__ bf16_t Os[2][64][136];
  __shared__ float in_s[2][160];
  __shared__ float vr_s[2][128];
  __shared__ float red[2][2][128];
  const int b = blockIdx.x >> 5, j0 = (blockIdx.x & 31) * 2;
  const int tid = threadIdx.x;
  const int lane = tid & 63, w = tid >> 6;
  const int quad = lane >> 4, l16 = lane & 15;
  f32x4 v0reg;
  if (tid < 16)
    v0reg = *(const f32x4*)&v0[(b * 64 + j0 + (tid >> 3)) * 32 + (tid & 7) * 4];
#pragma unroll
  for (int t = 0; t < 2; ++t) {
    int idx = tid + t * 256;
    int row = idx >> 3, off = (idx & 7) * 4;
    int jc = off >> 4, k = off & 15;
    f32x4 x = *(const f32x4*)&e0[((b * 64 + row) * 64 + j0) * 16 + off];
    bf16x4 y;
#pragma unroll
    for (int r = 0; r < 4; ++r) y[r] = (bf16_t)x[r];
    *(bf16x4*)&A0s[jc][row][k] = y;
    bf16x4 z = {(bf16_t)0.f, (bf16_t)0.f, (bf16_t)0.f, (bf16_t)0.f};
    *(bf16x4*)&A0s[jc][row][16 + k] = z;
  }
  const int c0[2] = {w * 32 + quad * 4, w * 32 + 16 + quad * 4};
  bf16x8 wf[2];
#pragma unroll
  for (int nt = 0; nt < 2; ++nt) {
    const int c = w * 32 + nt * 16 + l16;
#pragma unroll
    for (int jj = 0; jj < 8; ++jj)
      wf[nt][jj] = (quad < 2) ? (bf16_t)eW[(quad * 8 + jj) * 128 + c] : (bf16_t)0.f;
  }
  f32x4 acc[2][4][2];
  {
    f32x4 ebv[2], evj[2][2], evi[4][2];
#pragma unroll
    for (int nt = 0; nt < 2; ++nt) {
      ebv[nt] = *(const f32x4*)&eb[c0[nt]];
#pragma unroll
      for (int jc = 0; jc < 2; ++jc)
        evj[jc][nt] = *(const f32x4*)&evA[(b * 64 + j0 + jc) * 128 + c0[nt]];
#pragma unroll
      for (int mt = 0; mt < 4; ++mt)
        evi[mt][nt] = *(const f32x4*)&evA[(b * 64 + mt * 16 + l16) * 128 + c0[nt]];
    }
#pragma unroll
    for (int jc = 0; jc < 2; ++jc)
#pragma unroll
      for (int mt = 0; mt < 4; ++mt)
#pragma unroll
        for (int nt = 0; nt < 2; ++nt)
          acc[jc][mt][nt] = ebv[nt] + evj[jc][nt] + evi[mt][nt];
  }
  __syncthreads();
#pragma unroll
  for (int jc = 0; jc < 2; ++jc) {
#pragma unroll
    for (int mt = 0; mt < 4; ++mt) {
      bf16x8 ef = *(const bf16x8*)&A0s[jc][mt * 16 + l16][quad * 8];
#pragma unroll
      for (int nt = 0; nt < 2; ++nt)
        acc[jc][mt][nt] = __builtin_amdgcn_mfma_f32_16x16x32_bf16(wf[nt], ef, acc[jc][mt][nt], 0, 0, 0);
    }
  }
#pragma unroll
  for (int jc = 0; jc < 2; ++jc) {
#pragma unroll
    for (int nt = 0; nt < 2; ++nt) {
      f32x4 ps = {0.f, 0.f, 0.f, 0.f};
#pragma unroll
      for (int mt = 0; mt < 4; ++mt) {
        const int i = mt * 16 + l16;
        bf16x4 outv;
#pragma unroll
        for (int r = 0; r < 4; ++r) {
          float vv = fmaxf(acc[jc][mt][nt][r], 0.f);
          ps[r] += vv;
          outv[r] = (bf16_t)vv;
        }
        *(bf16x4*)&Os[jc][i][c0[nt]] = outv;
      }
#pragma unroll
      for (int m = 1; m <= 8; m <<= 1) {
#pragma unroll
        for (int r = 0; r < 4; ++r) ps[r] += __shfl_xor(ps[r], m);
      }
      if (l16 == 0) *(f32x4*)&in_s[jc][c0[nt]] = ps;
    }
  }
  if (tid < 16) *(f32x4*)&in_s[tid >> 3][128 + (tid & 7) * 4] = v0reg;
  __syncthreads();
  {
    bf16_t* ebase = &e_ws[((size_t)(b * 64 + j0) * 64) * 128];
#pragma unroll
    for (int t = 0; t < 8; ++t) {
      int idx = tid + t * 256;
      *(int4*)&ebase[idx * 8] =
          *(const int4*)&Os[idx >> 10][(idx >> 4) & 63][(idx & 15) * 8];
    }
  }
  const int khalf = w >> 1, cbase = (w & 1) << 6;
  const int cc = cbase + lane;
  const int c = tid & 127, h = tid >> 7;
  {  // tail1: vr = relu(concat(pve,v0)@vW + vb); K=160
    float p0 = 0.f, p1 = 0.f;
    const uint4* Wp = &g1_vWp[(khalf * 10) * 128 + cc];
    const float* xs0 = &in_s[0][khalf * 80];
    const float* xs1 = &in_s[1][khalf * 80];
#pragma unroll 5
    for (int k8 = 0; k8 < 10; ++k8) {
      uint4 wv = Wp[k8 * 128];
      float we0 = blo(wv.x), wo0 = bhi(wv.x);
      float we1 = blo(wv.y), wo1 = bhi(wv.y);
      float we2 = blo(wv.z), wo2 = bhi(wv.z);
      float we3 = blo(wv.w), wo3 = bhi(wv.w);
      float4 xa0 = *(const float4*)&xs0[k8 * 8];
      float4 xb0 = *(const float4*)&xs0[k8 * 8 + 4];
      float4 xa1 = *(const float4*)&xs1[k8 * 8];
      float4 xb1 = *(const float4*)&xs1[k8 * 8 + 4];
      p0 += xa0.x * we0 + xa0.y * wo0 + xa0.z * we1 + xa0.w * wo1
          + xb0.x * we2 + xb0.y * wo2 + xb0.z * we3 + xb0.w * wo3;
      p1 += xa1.x * we0 + xa1.y * wo0 + xa1.z * we1 + xa1.w * wo1
          + xb1.x * we2 + xb1.y * wo2 + xb1.z * we3 + xb1.w * wo3;
    }
    red[khalf][0][cc] = p0;
    red[khalf][1][cc] = p1;
  }
  bar_lgkm();
  {
    float vacc = vb[c] + red[0][h][c] + red[1][h][c];
    float vr = fmaxf(vacc, 0.f);
    v[(b * 64 + j0 + h) * 128 + c] = vr;
    vr_s[h][c] = vr;
  }
  bar_lgkm();
  {  // tail2: evB = vr @ evW0 + evb; K=128
    float p0 = 0.f, p1 = 0.f;
    const uint4* Wp = &evW0p[(khalf * 8) * 128 + cc];
    const float* xs0 = &vr_s[0][khalf << 6];
    const float* xs1 = &vr_s[1][khalf << 6];
#pragma unroll 4
    for (int k8 = 0; k8 < 8; ++k8) {
      uint4 wv = Wp[k8 * 128];
      float we0 = blo(wv.x), wo0 = bhi(wv.x);
      float we1 = blo(wv.y), wo1 = bhi(wv.y);
      float we2 = blo(wv.z), wo2 = bhi(wv.z);
      float we3 = blo(wv.w), wo3 = bhi(wv.w);
      float4 xa0 = *(const float4*)&xs0[k8 * 8];
      float4 xb0 = *(const float4*)&xs0[k8 * 8 + 4];
      float4 xa1 = *(const float4*)&xs1[k8 * 8];
      float4 xb1 = *(const float4*)&xs1[k8 * 8 + 4];
      p0 += xa0.x * we0 + xa0.y * wo0 + xa0.z * we1 + xa0.w * wo1
          + xb0.x * we2 + xb0.y * wo2 + xb0.z * we3 + xb0.w * wo3;
      p1 += xa1.x * we0 + xa1.y * wo0 + xa1.z * we1 + xa1.w * wo1
          + xb1.x * we2 + xb1.y * wo2 + xb1.z * we3 + xb1.w * wo3;
    }
    red[khalf][0][cc] = p0;
    red[khalf][1][cc] = p1;
  }
  bar_lgkm();
  evB[(b * 64 + j0 + h) * 128 + c] = evb[c] + red[0][h][c] + red[1][h][c];
}

// ------------- inner edge pass: 4 cols/block, 2 double-buffered pairs ------------------
// Block (b,j0): cols j0..j0+3 (two 2-col pairs). Pipeline: load0 | EVGEN |
// stage0 + issue load1 | MFMA0 | epi0 | write0 + stage1 | MFMA1 | epi1 |
// write1/edot | v-tails (2 rows x 2 pairs) + BN stats.
template <bool LAST, bool EVGEN>
__global__ __launch_bounds__(256, 2) void k_edge_inner(bf16_t* __restrict__ e_ws,
    const bf16_t* __restrict__ Wt, const float* __restrict__ eb,
    const float* __restrict__ ev, const float* __restrict__ eW3,
    float* __restrict__ edt, const float* __restrict__ vin,
    float* __restrict__ vout, const uint4* __restrict__ vWp,
    const float* __restrict__ vb, float* __restrict__ statsAcc,
    const float* __restrict__ statsPrev, const float* __restrict__ gPrev,
    const float* __restrict__ btPrev, const bf16_t* __restrict__ evWtB,
    const float* __restrict__ evb) {
  __shared__ bf16_t As[2][2][64][136];   // [pair][jc][i][c]; As[1][1] doubles as vbn stage
  __shared__ float W3s[128];
  __shared__ float in_s[2][2][256];      // [pair][jc][ pve(128) | vbn_row(128) ]
  __shared__ float red[2][2][128];
  __shared__ float part[4][2];
  __shared__ float scs[64], shs[64];
  const int b = blockIdx.x >> 4, j0 = (blockIdx.x & 15) * 4;
  const int tid = threadIdx.x;
  const int lane = tid & 63, w = tid >> 6;
  const int quad = lane >> 4, l16 = lane & 15;
  bf16_t* ebase0 = &e_ws[((size_t)(b * 64 + j0) * 64) * 128];
  bf16_t* ebase1 = ebase0 + 2 * 64 * 128;
  // issue pair0 e loads
  int4 stg[8];
#pragma unroll
  for (int t = 0; t < 8; ++t)
    stg[t] = *(const int4*)&ebase0[(tid + t * 256) * 8];
  // v rows j0..j0+3 for residual (tid<128: row = tid>>5)
  f32x4 vreg;
  if (tid < 128)
    vreg = *(const f32x4*)&vin[(b * 64 + j0 + (tid >> 5)) * 128 + (tid & 31) * 4];
  if (LAST) {
    if (tid < 128) W3s[tid] = eW3[tid];
  }
  bf16x8 wf[2][4];
#pragma unroll
  for (int nt = 0; nt < 2; ++nt)
#pragma unroll
    for (int ks = 0; ks < 4; ++ks)
      wf[nt][ks] = *(const bf16x8*)&Wt[(w * 32 + nt * 16 + l16) * 128 + ks * 32 + quad * 8];
  const int c0[2] = {w * 32 + quad * 4, w * 32 + 16 + quad * 4};
  f32x4 ebv[2];
#pragma unroll
  for (int nt = 0; nt < 2; ++nt) ebv[nt] = *(const f32x4*)&eb[c0[nt]];
  f32x4 acc_ev[4][2];   // ev_i fragments (incl. evb)
  f32x4 evj[4][2];      // ev rows j0..j0+3 (incl. evb)
  if (EVGEN) {
    if (tid < 64) {
      float mu = statsPrev[tid] * (1.f / 8192.f);
      float var = statsPrev[64 + tid] * (1.f / 8192.f) - mu * mu;
      float sc = rsqrtf(var + 128.f) * gPrev[tid];
      scs[tid] = sc;
      shs[tid] = btPrev[tid] - mu * sc;
    }
    bf16x8 wf2[2][4];
#pragma unroll
    for (int nt = 0; nt < 2; ++nt)
#pragma unroll
      for (int ks = 0; ks < 4; ++ks)
        wf2[nt][ks] = *(const bf16x8*)&evWtB[(w * 32 + nt * 16 + l16) * 128 + ks * 32 + quad * 8];
    bar_lgkm();  // scs/shs ready
    // stage vbn = BN(vin[b]) bf16 into As[1][1] (overwritten later by pair1 e)
#pragma unroll
    for (int t = 0; t < 16; ++t) {
      int row = t * 4 + w;
      float2 xv = *(const float2*)&vin[(b * 64 + row) * 128 + lane * 2];
      float sc = scs[row], sh = shs[row];
      bf16x2 o;
      o[0] = (bf16_t)(xv.x * sc + sh);
      o[1] = (bf16_t)(xv.y * sc + sh);
      *(bf16x2*)&As[1][1][row][lane * 2] = o;
    }
    if (tid < 128) {  // BN own rows for residual/concat
      int rr = j0 + (tid >> 5);
      vreg = vreg * scs[rr] + shs[rr];
    }
    bar_lgkm();  // vbn staged
#pragma unroll
    for (int nt = 0; nt < 2; ++nt) {
      f32x4 bias = *(const f32x4*)&evb[c0[nt]];
#pragma unroll
      for (int mt = 0; mt < 4; ++mt) acc_ev[mt][nt] = bias;
    }
#pragma unroll
    for (int ks = 0; ks < 4; ++ks) {
      bf16x8 bfm[4];
#pragma unroll
      for (int mt = 0; mt < 4; ++mt)
        bfm[mt] = *(const bf16x8*)&As[1][1][mt * 16 + l16][ks * 32 + quad * 8];
#pragma unroll
      for (int mt = 0; mt < 4; ++mt)
#pragma unroll
        for (int nt = 0; nt < 2; ++nt)
          acc_ev[mt][nt] = __builtin_amdgcn_mfma_f32_16x16x32_bf16(wf2[nt][ks], bfm[mt], acc_ev[mt][nt], 0, 0, 0);
    }
    // ev rows j0..j0+3 all live in tile mtj = j0>>4 (j0 % 4 == 0)
    const int mtj = j0 >> 4;
    f32x4 evrow[2];
#pragma unroll
    for (int mt = 0; mt < 4; ++mt)
      if (mtj == mt) { evrow[0] = acc_ev[mt][0]; evrow[1] = acc_ev[mt][1]; }
#pragma unroll
    for (int jj = 0; jj < 4; ++jj) {
      int src = (quad << 4) | ((j0 + jj) & 15);
#pragma unroll
      for (int nt = 0; nt < 2; ++nt)
#pragma unroll
        for (int r = 0; r < 4; ++r)
          evj[jj][nt][r] = __shfl(evrow[nt][r], src);
    }
  } else {
#pragma unroll
    for (int nt = 0; nt < 2; ++nt) {
#pragma unroll
      for (int jj = 0; jj < 4; ++jj)
        evj[jj][nt] = *(const f32x4*)&ev[(b * 64 + j0 + jj) * 128 + c0[nt]];
#pragma unroll
      for (int mt = 0; mt < 4; ++mt)
        acc_ev[mt][nt] = *(const f32x4*)&ev[(b * 64 + mt * 16 + l16) * 128 + c0[nt]];
    }
  }
  // stage pair0 e -> As[0]
#pragma unroll
  for (int t = 0; t < 8; ++t) {
    int idx = tid + t * 256;
    *(int4*)&As[0][idx >> 10][(idx >> 4) & 63][(idx & 15) * 8] = stg[t];
  }
  // issue pair1 e loads (reuse stg; overlaps MFMA0/epi0 below)
#pragma unroll
  for (int t = 0; t < 8; ++t)
    stg[t] = *(const int4*)&ebase1[(tid + t * 256) * 8];
  // acc0 init
  f32x4 acc[2][4][2];
#pragma unroll
  for (int jc = 0; jc < 2; ++jc)
#pragma unroll
    for (int mt = 0; mt < 4; ++mt)
#pragma unroll
      for (int nt = 0; nt < 2; ++nt)
        acc[jc][mt][nt] = ebv[nt] + evj[jc][nt] + acc_ev[mt][nt];
  bar_lgkm();  // As[0] staged (+ EVGEN reads of As[1][1] complete)
  // MFMA0
#pragma unroll
  for (int ks = 0; ks < 4; ++ks) {
    bf16x8 ef[2][4];
#pragma unroll
    for (int jc = 0; jc < 2; ++jc)
#pragma unroll
      for (int mt = 0; mt < 4; ++mt)
        ef[jc][mt] = *(const bf16x8*)&As[0][jc][mt * 16 + l16][ks * 32 + quad * 8];
#pragma unroll
    for (int jc = 0; jc < 2; ++jc)
#pragma unroll
      for (int mt = 0; mt < 4; ++mt)
#pragma unroll
        for (int nt = 0; nt < 2; ++nt)
          acc[jc][mt][nt] = __builtin_amdgcn_mfma_f32_16x16x32_bf16(wf[nt][ks], ef[jc][mt], acc[jc][mt][nt], 0, 0, 0);
  }
  bar_lgkm();
  // epilogue0: relu, pve->in_s[0], residual into As[0]
#pragma unroll
  for (int jc = 0; jc < 2; ++jc) {
#pragma unroll
    for (int nt = 0; nt < 2; ++nt) {
      f32x4 ps = {0.f, 0.f, 0.f, 0.f};
#pragma unroll
      for (int mt = 0; mt < 4; ++mt) {
        const int i = mt * 16 + l16;
        bf16x4 eo = *(const bf16x4*)&As[0][jc][i][c0[nt]];
        bf16x4 outv;
#pragma unroll
        for (int r = 0; r < 4; ++r) {
          float vv = fmaxf(acc[jc][mt][nt][r], 0.f);
          ps[r] += vv;
          outv[r] = (bf16_t)(vv + (float)eo[r]);
        }
        *(bf16x4*)&As[0][jc][i][c0[nt]] = outv;
      }
#pragma unroll
      for (int m = 1; m <= 8; m <<= 1) {
#pragma unroll
        for (int r = 0; r < 4; ++r) ps[r] += __shfl_xor(ps[r], m);
      }
      if (l16 == 0) *(f32x4*)&in_s[0][jc][c0[nt]] = ps;
    }
  }
  bar_lgkm();  // As[0] residual-updated
  // write0 (overlaps MFMA1) + stage pair1 -> As[1]
  if (!LAST) {
#pragma unroll
    for (int t = 0; t < 8; ++t) {
      int idx = tid + t * 256;
      *(int4*)&ebase0[idx * 8] =
          *(const int4*)&As[0][idx >> 10][(idx >> 4) & 63][(idx & 15) * 8];
    }
  }
#pragma unroll
  for (int t = 0; t < 8; ++t) {
    int idx = tid + t * 256;
    *(int4*)&As[1][idx >> 10][(idx >> 4) & 63][(idx & 15) * 8] = stg[t];
  }
  // acc1 init
#pragma unroll
  for (int jc = 0; jc < 2; ++jc)
#pragma unroll
    for (int mt = 0; mt < 4; ++mt)
#pragma unroll
      for (int nt = 0; nt < 2; ++nt)
        acc[jc][mt][nt] = ebv[nt] + evj[2 + jc][nt] + acc_ev[mt][nt];
  bar_lgkm();  // As[1] staged
  // MFMA1
#pragma unroll
  for (int ks = 0; ks < 4; ++ks) {
    bf16x8 ef[2][4];
#pragma unroll
    for (int jc = 0; jc < 2; ++jc)
#pragma unroll
      for (int mt = 0; mt < 4; ++mt)
        ef[jc][mt] = *(const bf16x8*)&As[1][jc][mt * 16 + l16][ks * 32 + quad * 8];
#pragma unroll
    for (int jc = 0; jc < 2; ++jc)
#pragma unroll
      for (int mt = 0; mt < 4; ++mt)
#pragma unroll
        for (int nt = 0; nt < 2; ++nt)
          acc[jc][mt][nt] = __builtin_amdgcn_mfma_f32_16x16x32_bf16(wf[nt][ks], ef[jc][mt], acc[jc][mt][nt], 0, 0, 0);
  }
  bar_lgkm();
  // epilogue1
#pragma unroll
  for (int jc = 0; jc < 2; ++jc) {
#pragma unroll
    for (int nt = 0; nt < 2; ++nt) {
      f32x4 ps = {0.f, 0.f, 0.f, 0.f};
#pragma unroll
      for (int mt = 0; mt < 4; ++mt) {
        const int i = mt * 16 + l16;
        bf16x4 eo = *(const bf16x4*)&As[1][jc][i][c0[nt]];
        bf16x4 outv;
#pragma unroll
        for (int r = 0; r < 4; ++r) {
          float vv = fmaxf(acc[jc][mt][nt][r], 0.f);
          ps[r] += vv;
          outv[r] = (bf16_t)(vv + (float)eo[r]);
        }
        *(bf16x4*)&As[1][jc][i][c0[nt]] = outv;
      }
#pragma unroll
      for (int m = 1; m <= 8; m <<= 1) {
#pragma unroll
        for (int r = 0; r < 4; ++r) ps[r] += __shfl_xor(ps[r], m);
      }
      if (l16 == 0) *(f32x4*)&in_s[1][jc][c0[nt]] = ps;
    }
  }
  bar_lgkm();  // As[1] residual-updated, in_s[1] pve ready
  if (!LAST) {
#pragma unroll
    for (int t = 0; t < 8; ++t) {
      int idx = tid + t * 256;
      *(int4*)&ebase1[idx * 8] =
          *(const int4*)&As[1][idx >> 10][(idx >> 4) & 63][(idx & 15) * 8];
    }
  } else {
    // edot for 4 cols from As[p][jc] (e_new kept in LDS)
    const int i = tid >> 2, q = tid & 3;
#pragma unroll
    for (int p = 0; p < 2; ++p) {
#pragma unroll
      for (int jc = 0; jc < 2; ++jc) {
        float d = 0.f;
#pragma unroll
        for (int t = 0; t < 4; ++t) {
          bf16x8 x = *(const bf16x8*)&As[p][jc][i][q * 32 + t * 8];
#pragma unroll
          for (int u = 0; u < 8; ++u) d += (float)x[u] * W3s[q * 32 + t * 8 + u];
        }
        d += __shfl_xor(d, 1);
        d += __shfl_xor(d, 2);
        if (q == 0) edt[(b * 64 + j0 + p * 2 + jc) * 64 + i] = d;
      }
    }
  }
  // stash v rows into in_s[p][jc][128..]
  if (tid < 128) {
    int row = tid >> 5;
    *(f32x4*)&in_s[row >> 1][row & 1][128 + (tid & 31) * 4] = vreg;
  }
  bar_lgkm();
  // v-tails: per pair, packed-bf16 matvec with 2-way k-split
  const int khalf = w >> 1, cbase = (w & 1) << 6;
  const int cc = cbase + lane;
  const int c = tid & 127, h = tid >> 7;
#pragma unroll
  for (int p = 0; p < 2; ++p) {
    float p0 = 0.f, p1 = 0.f;
    {
      const uint4* Wp = &vWp[(khalf * 16) * 128 + cc];
      const float* xs0 = &in_s[p][0][khalf << 7];
      const float* xs1 = &in_s[p][1][khalf << 7];
#pragma unroll 4
      for (int k8 = 0; k8 < 16; ++k8) {
        uint4 wv = Wp[k8 * 128];
        float we0 = blo(wv.x), wo0 = bhi(wv.x);
        float we1 = blo(wv.y), wo1 = bhi(wv.y);
        float we2 = blo(wv.z), wo2 = bhi(wv.z);
        float we3 = blo(wv.w), wo3 = bhi(wv.w);
        float4 xa0 = *(const float4*)&xs0[k8 * 8];
        float4 xb0 = *(const float4*)&xs0[k8 * 8 + 4];
        float4 xa1 = *(const float4*)&xs1[k8 * 8];
        float4 xb1 = *(const float4*)&xs1[k8 * 8 + 4];
        p0 += xa0.x * we0 + xa0.y * wo0 + xa0.z * we1 + xa0.w * wo1
            + xb0.x * we2 + xb0.y * wo2 + xb0.z * we3 + xb0.w * wo3;
        p1 += xa1.x * we0 + xa1.y * wo0 + xa1.z * we1 + xa1.w * wo1
            + xb1.x * we2 + xb1.y * wo2 + xb1.z * we3 + xb1.w * wo3;
      }
    }
    red[khalf][0][cc] = p0;
    red[khalf][1][cc] = p1;
    bar_lgkm();
    float vacc = vb[c] + red[0][h][c] + red[1][h][c];
    float vnew = fmaxf(vacc, 0.f) + in_s[p][h][128 + c];
    vout[(b * 64 + j0 + p * 2 + h) * 128 + c] = vnew;
    float s = vnew, s2 = vnew * vnew;
#pragma unroll
    for (int m = 1; m <= 32; m <<= 1) {
      s += __shfl_xor(s, m);
      s2 += __shfl_xor(s2, m);
    }
    if (lane == 0) { part[w][0] = s; part[w][1] = s2; }
    bar_lgkm();
    if (tid < 2) {
      int n = j0 + p * 2 + tid;
      atomicAdd(&statsAcc[n], part[tid * 2][0] + part[tid * 2 + 1][0]);
      atomicAdd(&statsAcc[64 + n], part[tid * 2][1] + part[tid * 2 + 1][1]);
    }
    if (p == 0) bar_lgkm();  // red/part consumed before pair1 overwrites
  }
}

// ------------- g3 final (round-0 form) -------------
__global__ __launch_bounds__(256) void k_g3(const float* __restrict__ vv,
    const float* __restrict__ stats3, const float* __restrict__ g,
    const float* __restrict__ bt, const float* __restrict__ evW3,
    const float* __restrict__ evb3, const float* __restrict__ eb3,
    const float* __restrict__ edt, const float* __restrict__ vW3,
    const float* __restrict__ vb3, float* __restrict__ out_v,
    float* __restrict__ out_e) {
  __shared__ float vbn[64][132];
  __shared__ float edts[64][68];
  __shared__ float scs[64], shs[64];
  __shared__ float W3e[128];
  __shared__ float vWs[132];
  __shared__ float ev3s[64];
  __shared__ float pj[4][64];
  const int b = blockIdx.x, tid = threadIdx.x;
  if (tid < 64) {
    float mu = stats3[tid] * (1.f / 8192.f);
    float var = stats3[64 + tid] * (1.f / 8192.f) - mu * mu;
    float sc = rsqrtf(var + 128.f) * g[tid];
    scs[tid] = sc;
    shs[tid] = bt[tid] - mu * sc;
  }
  if (tid < 128) W3e[tid] = evW3[tid];
  if (tid < 129) vWs[tid] = vW3[tid];
  __syncthreads();
#pragma unroll
  for (int t = 0; t < 8; ++t) {
    int idx = t * 1024 + tid * 4;
    int row = idx >> 7, cc = idx & 127;
    f32x4 x = *(const f32x4*)&vv[(b * 64 + row) * 128 + cc];
    *(f32x4*)&vbn[row][cc] = x * scs[row] + shs[row];
  }
#pragma unroll
  for (int t = 0; t < 4; ++t) {
    int idx = t * 1024 + tid * 4;
    int j = idx >> 6, i = idx & 63;
    *(f32x4*)&edts[j][i] = *(const f32x4*)&edt[(b * 64 + j) * 64 + i];
  }
  __syncthreads();
  {
    int i = tid >> 2, q = tid & 3;
    float d = 0.f;
#pragma unroll
    for (int u = 0; u < 32; ++u) d += vbn[i][q * 32 + u] * W3e[q * 32 + u];
    d += __shfl_xor(d, 1);
    d += __shfl_xor(d, 2);
    if (q == 0) ev3s[i] = d + evb3[0];
  }
  __syncthreads();
  {
    int q = tid >> 6, j = tid & 63;
    float s = 0.f;
    const float e3 = eb3[0];
    const float evj = ev3s[j];
#pragma unroll
    for (int r = 0; r < 16; ++r) {
      int i = q * 16 + r;
      float val = edts[j][i] + e3 + ev3s[i] + evj;
      out_e[(b * 64 + i) * 64 + j] = val;
      s += val;
    }
    pj[q][j] = s;
  }
  __syncthreads();
  {
    int n = tid >> 2, q = tid & 3;
    float d = 0.f;
#pragma unroll
    for (int u = 0; u < 32; ++u) d += vbn[n][q * 32 + u] * vWs[1 + q * 32 + u];
    d += __shfl_xor(d, 1);
    d += __shfl_xor(d, 2);
    if (q == 0) {
      float p3 = pj[0][n] + pj[1][n] + pj[2][n] + pj[3][n];
      out_v[b * 64 + n] = d + p3 * vWs[0] + vb3[0];
    }
  }
}

extern "C" void kernel_launch(void* const* d_in, const int* in_sizes, int n_in,
                              void* d_out, int out_size, void* d_ws, size_t ws_size,
                              hipStream_t stream) {
  const float* in_v    = (const float*)d_in[0];
  const float* in_e    = (const float*)d_in[1];
  const float* bn_in_g = (const float*)d_in[2];
  const float* bn_in_b = (const float*)d_in[3];
  const float* g1_evW  = (const float*)d_in[4];
  const float* g1_evb  = (const float*)d_in[5];
  const float* g1_eW   = (const float*)d_in[6];
  const float* g1_eb   = (const float*)d_in[7];
  const float* g1_vW   = (const float*)d_in[8];
  const float* g1_vb   = (const float*)d_in[9];
  const float* inn_evW = (const float*)d_in[10];
  const float* inn_evb = (const float*)d_in[11];
  const float* inn_eW  = (const float*)d_in[12];
  const float* inn_eb  = (const float*)d_in[13];
  const float* inn_vW  = (const float*)d_in[14];
  const float* inn_vb  = (const float*)d_in[15];
  const float* bn_g    = (const float*)d_in[16];
  const float* bn_b    = (const float*)d_in[17];
  const float* g3_evW  = (const float*)d_in[18];
  const float* g3_evb  = (const float*)d_in[19];
  const float* g3_eW   = (const float*)d_in[20];
  const float* g3_eb   = (const float*)d_in[21];
  const float* g3_vW   = (const float*)d_in[22];
  const float* g3_vb   = (const float*)d_in[23];

  char* ws = (char*)d_ws;
  bf16_t* e_ws = (bf16_t*)(ws);                       // 64MB
  float* vA       = (float*)(ws + 67108864);          // 2MB (v ping)
  float* evA      = (float*)(ws + 69206016);          // 2MB : g1's ev
  float* evB      = (float*)(ws + 71303168);          // 2MB : layer-0 ev
  float* v0       = (float*)(ws + 73400320);          // 512KB
  bf16_t* Wt      = (bf16_t*)(ws + 73924608);         // 128KB
  float* edt      = (float*)(ws + 74055680);          // 1MB
  float* stats    = (float*)(ws + 75104256);          // 2KB
  unsigned* vWp   = (unsigned*)(ws + 75106304);       // 256KB
  unsigned* g1_vWp= (unsigned*)(ws + 75368448);       // 40KB
  unsigned* evWp  = (unsigned*)(ws + 75409408);       // 128KB
  bf16_t* evWtB   = (bf16_t*)(ws + 75540480);         // 128KB
  float* vB       = (float*)(ws + 75671552);          // 2MB (v pong)

  float* out_v = (float*)d_out;
  float* out_e = (float*)d_out + 4096;

  k_prep<<<945, 256, 0, stream>>>(in_v, bn_in_g, bn_in_b, inn_eW, inn_vW, g1_vW,
                                  inn_evW, v0, Wt, stats, vWp, g1_vWp, evWp, evWtB);

  // ---- g1 (edge + fused v -> vA + fused layer-0 ev -> evB) ----
  k_ev<32><<<512, 256, 0, stream>>>(v0, g1_evW, g1_evb, evA);
  k_edge_g1<<<2048, 256, 0, stream>>>(in_e, g1_eW, g1_eb, evA, e_ws,
                                      v0, (const uint4*)g1_vWp, g1_vb,
                                      (const uint4*)evWp, inn_evb, vA, evB);

  // ---- inner layers: 1024 blocks x 4 cols, v ping-pong ----
  float* vbufs[2] = {vA, vB};
  for (int l = 0; l < 4; ++l) {
    float* vin_l  = vbufs[l & 1];
    float* vout_l = vbufs[(l + 1) & 1];
    if (l == 0)
      k_edge_inner<false, false><<<1024, 256, 0, stream>>>(e_ws, Wt,
          inn_eb, evB, g3_eW, edt, vin_l, vout_l,
          (const uint4*)vWp, inn_vb, stats,
          nullptr, nullptr, nullptr, nullptr, nullptr);
    else if (l < 3)
      k_edge_inner<false, true><<<1024, 256, 0, stream>>>(e_ws, Wt + l * 16384,
          inn_eb + l * 128, evB, g3_eW, edt, vin_l, vout_l,
          (const uint4*)vWp + l * 4096, inn_vb + l * 128, stats + l * 128,
          stats + (l - 1) * 128, bn_g + (l - 1) * 64, bn_b + (l - 1) * 64,
          evWtB + l * 16384, inn_evb + l * 128);
    else
      k_edge_inner<true, true><<<1024, 256, 0, stream>>>(e_ws, Wt + l * 16384,
          inn_eb + l * 128, evB, g3_eW, edt, vin_l, vout_l,
          (const uint4*)vWp + l * 4096, inn_vb + l * 128, stats + l * 128,
          stats + (l - 1) * 128, bn_g + (l - 1) * 64, bn_b + (l - 1) * 64,
          evWtB + l * 16384, inn_evb + l * 128);
  }

  // ---- g3 final (v after l=3 lands in vA) ----
  k_g3<<<64, 256, 0, stream>>>(vA, stats + 384, bn_g + 192, bn_b + 192,
                               g3_evW, g3_evb, g3_eb, edt, g3_vW, g3_vb,
                               out_v, out_e);
}

// Round 11
// 367.938 us; speedup vs baseline: 1.0222x; 1.0222x over previous
//
#include <hip/hip_runtime.h>
#include <hip/hip_bf16.h>

// GraphVertEdgeNet on MI355X. B=64, N=64, VF=32, EF=16, DV=DE=128, LN=4.
// e stored bf16 in ws (64MB) in TRANSPOSED layout e_t[b][j][i][c].
// Round-11: restore round-8 (best measured passing config: 367.5us, 8
// dispatches, 2 cols/block, 40KB LDS, 4 blocks/CU, fused v-tails + EVGEN,
// packed-bf16 tail weights). k_edge_inner is UNSWIZZLED: round-10 showed
// that permuting its block order reorders the BN-stats atomicAdd float
// sums and pushes the thin bf16 e-path precision margin over threshold
// (9.5e-4 > 7e-4). T1 swizzle kept ONLY on k_edge_g1, which has no atomics
// and no intra-dispatch cross-block reads -> bitwise-identical output.

typedef __bf16 bf16_t;
typedef __bf16 bf16x8 __attribute__((ext_vector_type(8)));
typedef __bf16 bf16x4 __attribute__((ext_vector_type(4)));
typedef __bf16 bf16x2 __attribute__((ext_vector_type(2)));
typedef float f32x4 __attribute__((ext_vector_type(4)));

__device__ __forceinline__ void bar_lgkm() {
  asm volatile("s_waitcnt lgkmcnt(0)\n\ts_barrier" ::: "memory");
}

__device__ __forceinline__ unsigned pack2(float a, float b) {
  bf16_t ba = (bf16_t)a, bb = (bf16_t)b;
  unsigned short ua, ub;
  __builtin_memcpy(&ua, &ba, 2);
  __builtin_memcpy(&ub, &bb, 2);
  return (unsigned)ua | ((unsigned)ub << 16);
}
__device__ __forceinline__ float blo(unsigned u) {
  unsigned v = u << 16; float f; __builtin_memcpy(&f, &v, 4); return f;
}
__device__ __forceinline__ float bhi(unsigned u) {
  unsigned v = u & 0xffff0000u; float f; __builtin_memcpy(&f, &v, 4); return f;
}

// ---------------- prep: input BN (v0), transposes, packed weights, zero stats ----------
__global__ __launch_bounds__(256) void k_prep(const float* __restrict__ vin,
    const float* __restrict__ g, const float* __restrict__ bt,
    const float* __restrict__ eW, const float* __restrict__ inn_vW,
    const float* __restrict__ g1_vW, const float* __restrict__ inn_evW,
    float* __restrict__ v0, bf16_t* __restrict__ Wt, float* __restrict__ stats,
    unsigned* __restrict__ vWp, unsigned* __restrict__ g1_vWp,
    unsigned* __restrict__ evWp, bf16_t* __restrict__ evWtB) {
  const int blk = blockIdx.x, tid = threadIdx.x;
  if (blk < 8) {  // BatchNorm1d(N*VF) over batch
    int ch = blk * 256 + tid;
    float s = 0.f, s2 = 0.f;
    for (int b = 0; b < 64; ++b) { float x = vin[b * 2048 + ch]; s += x; s2 += x * x; }
    float mu = s * (1.f / 64.f);
    float var = s2 * (1.f / 64.f) - mu * mu;
    float sc = rsqrtf(var + 1e-5f) * g[ch];
    float bb = bt[ch];
    for (int b = 0; b < 64; ++b) {
      float x = vin[b * 2048 + ch];
      v0[b * 2048 + ch] = (x - mu) * sc + bb;
    }
  } else if (blk < 264) {  // Wt[l][n][k] = eW[l][k][n] bf16 (edge MFMA A-frags)
    int idx = (blk - 8) * 256 + tid;
    int l = idx >> 14, r = idx & 16383, n = r >> 7, k = r & 127;
    Wt[idx] = (bf16_t)eW[(l << 14) + (k << 7) + n];
  } else if (blk == 264) {  // zero stats
    for (int i = tid; i < 512; i += 256) stats[i] = 0.f;
  } else if (blk < 521) {  // vWp: inn_vW [4][256][128] packed bf16 pairs
    int idx = (blk - 265) * 256 + tid;
    int l = idx >> 14, r = idx & 16383;
    int k8 = r >> 9, c = (r >> 2) & 127, j = r & 3;
    int ka = k8 * 8 + j * 2;
    vWp[idx] = pack2(inn_vW[(l << 15) + ka * 128 + c],
                     inn_vW[(l << 15) + (ka + 1) * 128 + c]);
  } else if (blk < 561) {  // g1_vWp: g1_vW [160][128] packed
    int idx = (blk - 521) * 256 + tid;
    int k8 = idx >> 9, c = (idx >> 2) & 127, j = idx & 3;
    int ka = k8 * 8 + j * 2;
    g1_vWp[idx] = pack2(g1_vW[ka * 128 + c], g1_vW[(ka + 1) * 128 + c]);
  } else if (blk < 689) {  // evWp: inn_evW [4][128][128] packed (g1 tail2 uses l=0)
    int idx = (blk - 561) * 256 + tid;
    int l = idx >> 13, r = idx & 8191;
    int k8 = r >> 9, c = (r >> 2) & 127, j = r & 3;
    int ka = k8 * 8 + j * 2;
    evWp[idx] = pack2(inn_evW[(l << 14) + ka * 128 + c],
                      inn_evW[(l << 14) + (ka + 1) * 128 + c]);
  } else {  // evWtB[l][n][k] = inn_evW[l][k][n] bf16 (ev MFMA A-frags)
    int idx = (blk - 689) * 256 + tid;  // 65536
    int l = idx >> 14, r = idx & 16383, n = r >> 7, k = r & 127;
    evWtB[idx] = (bf16_t)inn_evW[(l << 14) + (k << 7) + n];
  }
}

// ------------- ev = v_in @ W + bias : [4096,32]@[32,128] (g1 only). 8 rows/blk -------------
template <int K>
__global__ __launch_bounds__(256) void k_ev(const float* __restrict__ v_in,
    const float* __restrict__ W, const float* __restrict__ bias,
    float* __restrict__ out) {
  __shared__ float rows_s[8][K];
  const int r0 = blockIdx.x * 8;
  const int tid = threadIdx.x;
  const int c = tid & 127, h = tid >> 7;
  for (int idx = tid; idx < 8 * K; idx += 256) {
    int rr = idx / K, kk = idx % K;
    rows_s[rr][kk] = v_in[(r0 + rr) * K + kk];
  }
  __syncthreads();
  float acc[4];
  const float bv = bias[c];
#pragma unroll
  for (int r = 0; r < 4; ++r) acc[r] = bv;
  for (int k4 = 0; k4 < K; k4 += 4) {
    float w0 = W[(k4 + 0) * 128 + c], w1 = W[(k4 + 1) * 128 + c];
    float w2 = W[(k4 + 2) * 128 + c], w3 = W[(k4 + 3) * 128 + c];
#pragma unroll
    for (int r = 0; r < 4; ++r) {
      float4 x = *(const float4*)&rows_s[h * 4 + r][k4];
      acc[r] += x.x * w0 + x.y * w1 + x.z * w2 + x.w * w3;
    }
  }
#pragma unroll
  for (int r = 0; r < 4; ++r) out[(r0 + h * 4 + r) * 128 + c] = acc[r];
}

// ------------- g1 edge pass + fused g1-v + layer-0 ev (+T1 swizzle, atomics-free:
// output bitwise identical under block permutation) ------
__global__ __launch_bounds__(256) void k_edge_g1(const float* __restrict__ e0,
    const float* __restrict__ eW, const float* __restrict__ eb,
    const float* __restrict__ evA, bf16_t* __restrict__ e_ws,
    const float* __restrict__ v0, const uint4* __restrict__ g1_vWp,
    const float* __restrict__ vb, const uint4* __restrict__ evW0p,
    const float* __restrict__ evb, float* __restrict__ v,
    float* __restrict__ evB) {
  __shared__ bf16_t A0s[2][64][40];
  __shared__ bf16_t Os[2][64][136];
  __shared__ float in_s[2][160];
  __shared__ float vr_s[2][128];
  __shared__ float red[2][2][128];
  // T1: XCD-contiguous block swizzle (2048 = 8 XCD x 256); safe: no atomics.
  const int wg = ((blockIdx.x & 7) << 8) | (blockIdx.x >> 3);
  const int b = wg >> 5, j0 = (wg & 31) * 2;
  const int tid = threadIdx.x;
  const int lane = tid & 63, w = tid >> 6;
  const int quad = lane >> 4, l16 = lane & 15;
  f32x4 v0reg;
  if (tid < 16)
    v0reg = *(const f32x4*)&v0[(b * 64 + j0 + (tid >> 3)) * 32 + (tid & 7) * 4];
#pragma unroll
  for (int t = 0; t < 2; ++t) {
    int idx = tid + t * 256;
    int row = idx >> 3, off = (idx & 7) * 4;
    int jc = off >> 4, k = off & 15;
    f32x4 x = *(const f32x4*)&e0[((b * 64 + row) * 64 + j0) * 16 + off];
    bf16x4 y;
#pragma unroll
    for (int r = 0; r < 4; ++r) y[r] = (bf16_t)x[r];
    *(bf16x4*)&A0s[jc][row][k] = y;
    bf16x4 z = {(bf16_t)0.f, (bf16_t)0.f, (bf16_t)0.f, (bf16_t)0.f};
    *(bf16x4*)&A0s[jc][row][16 + k] = z;
  }
  const int c0[2] = {w * 32 + quad * 4, w * 32 + 16 + quad * 4};
  bf16x8 wf[2];
#pragma unroll
  for (int nt = 0; nt < 2; ++nt) {
    const int c = w * 32 + nt * 16 + l16;
#pragma unroll
    for (int jj = 0; jj < 8; ++jj)
      wf[nt][jj] = (quad < 2) ? (bf16_t)eW[(quad * 8 + jj) * 128 + c] : (bf16_t)0.f;
  }
  f32x4 acc[2][4][2];
  {
    f32x4 ebv[2], evj[2][2], evi[4][2];
#pragma unroll
    for (int nt = 0; nt < 2; ++nt) {
      ebv[nt] = *(const f32x4*)&eb[c0[nt]];
#pragma unroll
      for (int jc = 0; jc < 2; ++jc)
        evj[jc][nt] = *(const f32x4*)&evA[(b * 64 + j0 + jc) * 128 + c0[nt]];
#pragma unroll
      for (int mt = 0; mt < 4; ++mt)
        evi[mt][nt] = *(const f32x4*)&evA[(b * 64 + mt * 16 + l16) * 128 + c0[nt]];
    }
#pragma unroll
    for (int jc = 0; jc < 2; ++jc)
#pragma unroll
      for (int mt = 0; mt < 4; ++mt)
#pragma unroll
        for (int nt = 0; nt < 2; ++nt)
          acc[jc][mt][nt] = ebv[nt] + evj[jc][nt] + evi[mt][nt];
  }
  __syncthreads();
#pragma unroll
  for (int jc = 0; jc < 2; ++jc) {
#pragma unroll
    for (int mt = 0; mt < 4; ++mt) {
      bf16x8 ef = *(const bf16x8*)&A0s[jc][mt * 16 + l16][quad * 8];
#pragma unroll
      for (int nt = 0; nt < 2; ++nt)
        acc[jc][mt][nt] = __builtin_amdgcn_mfma_f32_16x16x32_bf16(wf[nt], ef, acc[jc][mt][nt], 0, 0, 0);
    }
  }
#pragma unroll
  for (int jc = 0; jc < 2; ++jc) {
#pragma unroll
    for (int nt = 0; nt < 2; ++nt) {
      f32x4 ps = {0.f, 0.f, 0.f, 0.f};
#pragma unroll
      for (int mt = 0; mt < 4; ++mt) {
        const int i = mt * 16 + l16;
        bf16x4 outv;
#pragma unroll
        for (int r = 0; r < 4; ++r) {
          float vv = fmaxf(acc[jc][mt][nt][r], 0.f);
          ps[r] += vv;
          outv[r] = (bf16_t)vv;
        }
        *(bf16x4*)&Os[jc][i][c0[nt]] = outv;
      }
#pragma unroll
      for (int m = 1; m <= 8; m <<= 1) {
#pragma unroll
        for (int r = 0; r < 4; ++r) ps[r] += __shfl_xor(ps[r], m);
      }
      if (l16 == 0) *(f32x4*)&in_s[jc][c0[nt]] = ps;
    }
  }
  if (tid < 16) *(f32x4*)&in_s[tid >> 3][128 + (tid & 7) * 4] = v0reg;
  __syncthreads();
  {
    bf16_t* ebase = &e_ws[((size_t)(b * 64 + j0) * 64) * 128];
#pragma unroll
    for (int t = 0; t < 8; ++t) {
      int idx = tid + t * 256;
      *(int4*)&ebase[idx * 8] =
          *(const int4*)&Os[idx >> 10][(idx >> 4) & 63][(idx & 15) * 8];
    }
  }
  const int khalf = w >> 1, cbase = (w & 1) << 6;
  const int cc = cbase + lane;
  const int c = tid & 127, h = tid >> 7;
  {  // tail1: vr = relu(concat(pve,v0)@vW + vb); K=160
    float p0 = 0.f, p1 = 0.f;
    const uint4* Wp = &g1_vWp[(khalf * 10) * 128 + cc];
    const float* xs0 = &in_s[0][khalf * 80];
    const float* xs1 = &in_s[1][khalf * 80];
#pragma unroll 5
    for (int k8 = 0; k8 < 10; ++k8) {
      uint4 wv = Wp[k8 * 128];
      float we0 = blo(wv.x), wo0 = bhi(wv.x);
      float we1 = blo(wv.y), wo1 = bhi(wv.y);
      float we2 = blo(wv.z), wo2 = bhi(wv.z);
      float we3 = blo(wv.w), wo3 = bhi(wv.w);
      float4 xa0 = *(const float4*)&xs0[k8 * 8];
      float4 xb0 = *(const float4*)&xs0[k8 * 8 + 4];
      float4 xa1 = *(const float4*)&xs1[k8 * 8];
      float4 xb1 = *(const float4*)&xs1[k8 * 8 + 4];
      p0 += xa0.x * we0 + xa0.y * wo0 + xa0.z * we1 + xa0.w * wo1
          + xb0.x * we2 + xb0.y * wo2 + xb0.z * we3 + xb0.w * wo3;
      p1 += xa1.x * we0 + xa1.y * wo0 + xa1.z * we1 + xa1.w * wo1
          + xb1.x * we2 + xb1.y * wo2 + xb1.z * we3 + xb1.w * wo3;
    }
    red[khalf][0][cc] = p0;
    red[khalf][1][cc] = p1;
  }
  bar_lgkm();
  {
    float vacc = vb[c] + red[0][h][c] + red[1][h][c];
    float vr = fmaxf(vacc, 0.f);
    v[(b * 64 + j0 + h) * 128 + c] = vr;
    vr_s[h][c] = vr;
  }
  bar_lgkm();
  {  // tail2: evB = vr @ evW0 + evb; K=128
    float p0 = 0.f, p1 = 0.f;
    const uint4* Wp = &evW0p[(khalf * 8) * 128 + cc];
    const float* xs0 = &vr_s[0][khalf << 6];
    const float* xs1 = &vr_s[1][khalf << 6];
#pragma unroll 4
    for (int k8 = 0; k8 < 8; ++k8) {
      uint4 wv = Wp[k8 * 128];
      float we0 = blo(wv.x), wo0 = bhi(wv.x);
      float we1 = blo(wv.y), wo1 = bhi(wv.y);
      float we2 = blo(wv.z), wo2 = bhi(wv.z);
      float we3 = blo(wv.w), wo3 = bhi(wv.w);
      float4 xa0 = *(const float4*)&xs0[k8 * 8];
      float4 xb0 = *(const float4*)&xs0[k8 * 8 + 4];
      float4 xa1 = *(const float4*)&xs1[k8 * 8];
      float4 xb1 = *(const float4*)&xs1[k8 * 8 + 4];
      p0 += xa0.x * we0 + xa0.y * wo0 + xa0.z * we1 + xa0.w * wo1
          + xb0.x * we2 + xb0.y * wo2 + xb0.z * we3 + xb0.w * wo3;
      p1 += xa1.x * we0 + xa1.y * wo0 + xa1.z * we1 + xa1.w * wo1
          + xb1.x * we2 + xb1.y * wo2 + xb1.z * we3 + xb1.w * wo3;
    }
    red[khalf][0][cc] = p0;
    red[khalf][1][cc] = p1;
  }
  bar_lgkm();
  evB[(b * 64 + j0 + h) * 128 + c] = evb[c] + red[0][h][c] + red[1][h][c];
}

// ------------- inner edge pass + fused v-update & BN stats + (EVGEN) in-block ev -------
// UNSWIZZLED (round-8 block order): preserves the BN-stats atomicAdd ordering
// that the passing precision margin was measured under.
template <bool LAST, bool EVGEN>
__global__ __launch_bounds__(256) void k_edge_inner(bf16_t* __restrict__ e_ws,
    const bf16_t* __restrict__ Wt, const float* __restrict__ eb,
    const float* __restrict__ ev, const float* __restrict__ eW3,
    float* __restrict__ edt, const float* __restrict__ vin,
    float* __restrict__ vout, const uint4* __restrict__ vWp,
    const float* __restrict__ vb, float* __restrict__ statsAcc,
    const float* __restrict__ statsPrev, const float* __restrict__ gPrev,
    const float* __restrict__ btPrev, const bf16_t* __restrict__ evWtB,
    const float* __restrict__ evb) {
  __shared__ bf16_t As[2][64][136];   // [jc][i][c], +8 pad; As[0] doubles as vbn stage
  __shared__ float W3s[128];
  __shared__ float in_s[2][256];      // [jc][ pve(128) | vbn_row(128) ]
  __shared__ float red[2][2][128];
  __shared__ float part[4][2];
  __shared__ float scs[64], shs[64];
  const int b = blockIdx.x >> 5, j0 = (blockIdx.x & 31) * 2;
  const int tid = threadIdx.x;
  const int lane = tid & 63, w = tid >> 6;
  const int quad = lane >> 4, l16 = lane & 15;
  bf16_t* ebase = &e_ws[((size_t)(b * 64 + j0) * 64) * 128];
  // e-tile loads issued first (latency hidden under everything below)
  int4 stg[8];
#pragma unroll
  for (int t = 0; t < 8; ++t) {
    int idx = tid + t * 256;
    stg[t] = *(const int4*)&ebase[idx * 8];
  }
  f32x4 vreg;
  if (tid < 64)
    vreg = *(const f32x4*)&vin[(b * 64 + j0 + (tid >> 5)) * 128 + (tid & 31) * 4];
  if (LAST) {
    if (tid < 128) W3s[tid] = eW3[tid];
  }
  bf16x8 wf[2][4];
#pragma unroll
  for (int nt = 0; nt < 2; ++nt)
#pragma unroll
    for (int ks = 0; ks < 4; ++ks)
      wf[nt][ks] = *(const bf16x8*)&Wt[(w * 32 + nt * 16 + l16) * 128 + ks * 32 + quad * 8];
  const int c0[2] = {w * 32 + quad * 4, w * 32 + 16 + quad * 4};
  f32x4 acc[2][4][2];
  if (EVGEN) {
    // -------- in-block ev: BN(vin[b]) @ evW + evb, via MFMA --------
    if (tid < 64) {
      float mu = statsPrev[tid] * (1.f / 8192.f);
      float var = statsPrev[64 + tid] * (1.f / 8192.f) - mu * mu;
      float sc = rsqrtf(var + 128.f) * gPrev[tid];
      scs[tid] = sc;
      shs[tid] = btPrev[tid] - mu * sc;
    }
    bf16x8 wf2[2][4];
#pragma unroll
    for (int nt = 0; nt < 2; ++nt)
#pragma unroll
      for (int ks = 0; ks < 4; ++ks)
        wf2[nt][ks] = *(const bf16x8*)&evWtB[(w * 32 + nt * 16 + l16) * 128 + ks * 32 + quad * 8];
    bar_lgkm();  // scs/shs ready
    // stage vbn = BN(vin[b]) as bf16 into As[0]; wave w handles rows t*4+w
#pragma unroll
    for (int t = 0; t < 16; ++t) {
      int row = t * 4 + w;
      float2 xv = *(const float2*)&vin[(b * 64 + row) * 128 + lane * 2];
      float sc = scs[row], sh = shs[row];
      bf16x2 o;
      o[0] = (bf16_t)(xv.x * sc + sh);
      o[1] = (bf16_t)(xv.y * sc + sh);
      *(bf16x2*)&As[0][row][lane * 2] = o;
    }
    if (tid < 64) {  // BN own rows for residual/concat
      int rr = j0 + (tid >> 5);
      vreg = vreg * scs[rr] + shs[rr];
    }
    bar_lgkm();  // vbn staged
    f32x4 acc_ev[4][2];
#pragma unroll
    for (int nt = 0; nt < 2; ++nt) {
      f32x4 bias = *(const f32x4*)&evb[c0[nt]];
#pragma unroll
      for (int mt = 0; mt < 4; ++mt) acc_ev[mt][nt] = bias;
    }
#pragma unroll
    for (int ks = 0; ks < 4; ++ks) {
      bf16x8 bfm[4];
#pragma unroll
      for (int mt = 0; mt < 4; ++mt)
        bfm[mt] = *(const bf16x8*)&As[0][mt * 16 + l16][ks * 32 + quad * 8];
#pragma unroll
      for (int mt = 0; mt < 4; ++mt)
#pragma unroll
        for (int nt = 0; nt < 2; ++nt)
          acc_ev[mt][nt] = __builtin_amdgcn_mfma_f32_16x16x32_bf16(wf2[nt][ks], bfm[mt], acc_ev[mt][nt], 0, 0, 0);
    }
    // ev_j extraction: rows j0,j0+1 live in tile mtj at l16=(j0+jc)&15, same quad
    const int mtj = j0 >> 4;
    f32x4 evrow[2];
#pragma unroll
    for (int mt = 0; mt < 4; ++mt)
      if (mtj == mt) { evrow[0] = acc_ev[mt][0]; evrow[1] = acc_ev[mt][1]; }
    f32x4 evj[2][2];
#pragma unroll
    for (int jc = 0; jc < 2; ++jc) {
      int src = (quad << 4) | ((j0 + jc) & 15);
#pragma unroll
      for (int nt = 0; nt < 2; ++nt)
#pragma unroll
        for (int r = 0; r < 4; ++r)
          evj[jc][nt][r] = __shfl(evrow[nt][r], src);
    }
#pragma unroll
    for (int nt = 0; nt < 2; ++nt) {
      f32x4 ebv = *(const f32x4*)&eb[c0[nt]];
#pragma unroll
      for (int jc = 0; jc < 2; ++jc)
#pragma unroll
        for (int mt = 0; mt < 4; ++mt)
          acc[jc][mt][nt] = ebv + evj[jc][nt] + acc_ev[mt][nt];
    }
    bar_lgkm();  // all waves done reading As[0] (vbn) before e overwrites it
  } else {
    f32x4 ebv[2], evj[2][2], evi[4][2];
#pragma unroll
    for (int nt = 0; nt < 2; ++nt) {
      ebv[nt] = *(const f32x4*)&eb[c0[nt]];
#pragma unroll
      for (int jc = 0; jc < 2; ++jc)
        evj[jc][nt] = *(const f32x4*)&ev[(b * 64 + j0 + jc) * 128 + c0[nt]];
#pragma unroll
      for (int mt = 0; mt < 4; ++mt)
        evi[mt][nt] = *(const f32x4*)&ev[(b * 64 + mt * 16 + l16) * 128 + c0[nt]];
    }
#pragma unroll
    for (int jc = 0; jc < 2; ++jc)
#pragma unroll
      for (int mt = 0; mt < 4; ++mt)
#pragma unroll
        for (int nt = 0; nt < 2; ++nt)
          acc[jc][mt][nt] = ebv[nt] + evj[jc][nt] + evi[mt][nt];
  }
  // stage e tile into As
#pragma unroll
  for (int t = 0; t < 8; ++t) {
    int idx = tid + t * 256;
    *(int4*)&As[idx >> 10][(idx >> 4) & 63][(idx & 15) * 8] = stg[t];
  }
  bar_lgkm();
  // edge MFMA: D[c][i] = sum_k Wt[c][k] * e[i][k]
#pragma unroll
  for (int ks = 0; ks < 4; ++ks) {
    bf16x8 ef[2][4];
#pragma unroll
    for (int jc = 0; jc < 2; ++jc)
#pragma unroll
      for (int mt = 0; mt < 4; ++mt)
        ef[jc][mt] = *(const bf16x8*)&As[jc][mt * 16 + l16][ks * 32 + quad * 8];
#pragma unroll
    for (int jc = 0; jc < 2; ++jc)
#pragma unroll
      for (int mt = 0; mt < 4; ++mt)
#pragma unroll
        for (int nt = 0; nt < 2; ++nt)
          acc[jc][mt][nt] = __builtin_amdgcn_mfma_f32_16x16x32_bf16(wf[nt][ks], ef[jc][mt], acc[jc][mt][nt], 0, 0, 0);
  }
  bar_lgkm();
  // epilogue: relu, pve->LDS, residual, write cells back to As
#pragma unroll
  for (int jc = 0; jc < 2; ++jc) {
#pragma unroll
    for (int nt = 0; nt < 2; ++nt) {
      f32x4 ps = {0.f, 0.f, 0.f, 0.f};
#pragma unroll
      for (int mt = 0; mt < 4; ++mt) {
        const int i = mt * 16 + l16;
        bf16x4 eo = *(const bf16x4*)&As[jc][i][c0[nt]];
        bf16x4 outv;
#pragma unroll
        for (int r = 0; r < 4; ++r) {
          float vv = fmaxf(acc[jc][mt][nt][r], 0.f);
          ps[r] += vv;
          outv[r] = (bf16_t)(vv + (float)eo[r]);
        }
        *(bf16x4*)&As[jc][i][c0[nt]] = outv;
      }
#pragma unroll
      for (int m = 1; m <= 8; m <<= 1) {
#pragma unroll
        for (int r = 0; r < 4; ++r) ps[r] += __shfl_xor(ps[r], m);
      }
      if (l16 == 0) *(f32x4*)&in_s[jc][c0[nt]] = ps;
    }
  }
  if (tid < 64) *(f32x4*)&in_s[tid >> 5][128 + (tid & 31) * 4] = vreg;
  bar_lgkm();
  // v-update tail partials (packed bf16 weights, 2-way k-split)
  const int khalf = w >> 1, cbase = (w & 1) << 6;
  const int cc = cbase + lane;
  float p0 = 0.f, p1 = 0.f;
  {
    const uint4* Wp = &vWp[(khalf * 16) * 128 + cc];
    const float* xs0 = &in_s[0][khalf << 7];
    const float* xs1 = &in_s[1][khalf << 7];
#pragma unroll 4
    for (int k8 = 0; k8 < 16; ++k8) {
      uint4 wv = Wp[k8 * 128];
      float we0 = blo(wv.x), wo0 = bhi(wv.x);
      float we1 = blo(wv.y), wo1 = bhi(wv.y);
      float we2 = blo(wv.z), wo2 = bhi(wv.z);
      float we3 = blo(wv.w), wo3 = bhi(wv.w);
      float4 xa0 = *(const float4*)&xs0[k8 * 8];
      float4 xb0 = *(const float4*)&xs0[k8 * 8 + 4];
      float4 xa1 = *(const float4*)&xs1[k8 * 8];
      float4 xb1 = *(const float4*)&xs1[k8 * 8 + 4];
      p0 += xa0.x * we0 + xa0.y * wo0 + xa0.z * we1 + xa0.w * wo1
          + xb0.x * we2 + xb0.y * wo2 + xb0.z * we3 + xb0.w * wo3;
      p1 += xa1.x * we0 + xa1.y * wo0 + xa1.z * we1 + xa1.w * wo1
          + xb1.x * we2 + xb1.y * wo2 + xb1.z * we3 + xb1.w * wo3;
    }
  }
  if (!LAST) {
#pragma unroll
    for (int t = 0; t < 8; ++t) {
      int idx = tid + t * 256;
      *(int4*)&ebase[idx * 8] =
          *(const int4*)&As[idx >> 10][(idx >> 4) & 63][(idx & 15) * 8];
    }
  } else {
    const int i = tid >> 2, q = tid & 3;
#pragma unroll
    for (int jc = 0; jc < 2; ++jc) {
      float d = 0.f;
#pragma unroll
      for (int t = 0; t < 4; ++t) {
        bf16x8 x = *(const bf16x8*)&As[jc][i][q * 32 + t * 8];
#pragma unroll
        for (int u = 0; u < 8; ++u) d += (float)x[u] * W3s[q * 32 + t * 8 + u];
      }
      d += __shfl_xor(d, 1);
      d += __shfl_xor(d, 2);
      if (q == 0) edt[(b * 64 + j0 + jc) * 64 + i] = d;
    }
  }
  red[khalf][0][cc] = p0;
  red[khalf][1][cc] = p1;
  bar_lgkm();
  const int c = tid & 127, h = tid >> 7;
  float vacc = vb[c] + red[0][h][c] + red[1][h][c];
  float vnew = fmaxf(vacc, 0.f) + in_s[h][128 + c];  // relu + residual (BN'd v)
  vout[(b * 64 + j0 + h) * 128 + c] = vnew;
  float s = vnew, s2 = vnew * vnew;
#pragma unroll
  for (int m = 1; m <= 32; m <<= 1) {
    s += __shfl_xor(s, m);
    s2 += __shfl_xor(s2, m);
  }
  if (lane == 0) { part[w][0] = s; part[w][1] = s2; }
  bar_lgkm();
  if (tid < 2) {
    int n = j0 + tid;
    atomicAdd(&statsAcc[n], part[tid * 2][0] + part[tid * 2 + 1][0]);
    atomicAdd(&statsAcc[64 + n], part[tid * 2][1] + part[tid * 2 + 1][1]);
  }
}

// ------------- g3 final (round-0 form, reads vA + stats[3]) -------------
__global__ __launch_bounds__(256) void k_g3(const float* __restrict__ vv,
    const float* __restrict__ stats3, const float* __restrict__ g,
    const float* __restrict__ bt, const float* __restrict__ evW3,
    const float* __restrict__ evb3, const float* __restrict__ eb3,
    const float* __restrict__ edt, const float* __restrict__ vW3,
    const float* __restrict__ vb3, float* __restrict__ out_v,
    float* __restrict__ out_e) {
  __shared__ float vbn[64][132];
  __shared__ float edts[64][68];
  __shared__ float scs[64], shs[64];
  __shared__ float W3e[128];
  __shared__ float vWs[132];
  __shared__ float ev3s[64];
  __shared__ float pj[4][64];
  const int b = blockIdx.x, tid = threadIdx.x;
  if (tid < 64) {
    float mu = stats3[tid] * (1.f / 8192.f);
    float var = stats3[64 + tid] * (1.f / 8192.f) - mu * mu;
    float sc = rsqrtf(var + 128.f) * g[tid];
    scs[tid] = sc;
    shs[tid] = bt[tid] - mu * sc;
  }
  if (tid < 128) W3e[tid] = evW3[tid];
  if (tid < 129) vWs[tid] = vW3[tid];
  __syncthreads();
#pragma unroll
  for (int t = 0; t < 8; ++t) {
    int idx = t * 1024 + tid * 4;
    int row = idx >> 7, cc = idx & 127;
    f32x4 x = *(const f32x4*)&vv[(b * 64 + row) * 128 + cc];
    *(f32x4*)&vbn[row][cc] = x * scs[row] + shs[row];
  }
#pragma unroll
  for (int t = 0; t < 4; ++t) {
    int idx = t * 1024 + tid * 4;
    int j = idx >> 6, i = idx & 63;
    *(f32x4*)&edts[j][i] = *(const f32x4*)&edt[(b * 64 + j) * 64 + i];
  }
  __syncthreads();
  {
    int i = tid >> 2, q = tid & 3;
    float d = 0.f;
#pragma unroll
    for (int u = 0; u < 32; ++u) d += vbn[i][q * 32 + u] * W3e[q * 32 + u];
    d += __shfl_xor(d, 1);
    d += __shfl_xor(d, 2);
    if (q == 0) ev3s[i] = d + evb3[0];
  }
  __syncthreads();
  {
    int q = tid >> 6, j = tid & 63;
    float s = 0.f;
    const float e3 = eb3[0];
    const float evj = ev3s[j];
#pragma unroll
    for (int r = 0; r < 16; ++r) {
      int i = q * 16 + r;
      float val = edts[j][i] + e3 + ev3s[i] + evj;
      out_e[(b * 64 + i) * 64 + j] = val;
      s += val;
    }
    pj[q][j] = s;
  }
  __syncthreads();
  {
    int n = tid >> 2, q = tid & 3;
    float d = 0.f;
#pragma unroll
    for (int u = 0; u < 32; ++u) d += vbn[n][q * 32 + u] * vWs[1 + q * 32 + u];
    d += __shfl_xor(d, 1);
    d += __shfl_xor(d, 2);
    if (q == 0) {
      float p3 = pj[0][n] + pj[1][n] + pj[2][n] + pj[3][n];
      out_v[b * 64 + n] = d + p3 * vWs[0] + vb3[0];
    }
  }
}

extern "C" void kernel_launch(void* const* d_in, const int* in_sizes, int n_in,
                              void* d_out, int out_size, void* d_ws, size_t ws_size,
                              hipStream_t stream) {
  const float* in_v    = (const float*)d_in[0];
  const float* in_e    = (const float*)d_in[1];
  const float* bn_in_g = (const float*)d_in[2];
  const float* bn_in_b = (const float*)d_in[3];
  const float* g1_evW  = (const float*)d_in[4];
  const float* g1_evb  = (const float*)d_in[5];
  const float* g1_eW   = (const float*)d_in[6];
  const float* g1_eb   = (const float*)d_in[7];
  const float* g1_vW   = (const float*)d_in[8];
  const float* g1_vb   = (const float*)d_in[9];
  const float* inn_evW = (const float*)d_in[10];
  const float* inn_evb = (const float*)d_in[11];
  const float* inn_eW  = (const float*)d_in[12];
  const float* inn_eb  = (const float*)d_in[13];
  const float* inn_vW  = (const float*)d_in[14];
  const float* inn_vb  = (const float*)d_in[15];
  const float* bn_g    = (const float*)d_in[16];
  const float* bn_b    = (const float*)d_in[17];
  const float* g3_evW  = (const float*)d_in[18];
  const float* g3_evb  = (const float*)d_in[19];
  const float* g3_eW   = (const float*)d_in[20];
  const float* g3_eb   = (const float*)d_in[21];
  const float* g3_vW   = (const float*)d_in[22];
  const float* g3_vb   = (const float*)d_in[23];

  char* ws = (char*)d_ws;
  bf16_t* e_ws = (bf16_t*)(ws);                       // 64MB
  float* vA       = (float*)(ws + 67108864);          // 2MB (v ping)
  float* evA      = (float*)(ws + 69206016);          // 2MB : g1's ev
  float* evB      = (float*)(ws + 71303168);          // 2MB : layer-0 ev
  float* v0       = (float*)(ws + 73400320);          // 512KB
  bf16_t* Wt      = (bf16_t*)(ws + 73924608);         // 128KB
  float* edt      = (float*)(ws + 74055680);          // 1MB
  float* stats    = (float*)(ws + 75104256);          // 2KB
  unsigned* vWp   = (unsigned*)(ws + 75106304);       // 256KB
  unsigned* g1_vWp= (unsigned*)(ws + 75368448);       // 40KB
  unsigned* evWp  = (unsigned*)(ws + 75409408);       // 128KB
  bf16_t* evWtB   = (bf16_t*)(ws + 75540480);         // 128KB
  float* vB       = (float*)(ws + 75671552);          // 2MB (v pong)

  float* out_v = (float*)d_out;
  float* out_e = (float*)d_out + 4096;

  k_prep<<<945, 256, 0, stream>>>(in_v, bn_in_g, bn_in_b, inn_eW, inn_vW, g1_vW,
                                  inn_evW, v0, Wt, stats, vWp, g1_vWp, evWp, evWtB);

  // ---- g1 (edge + fused v -> vA + fused layer-0 ev -> evB) ----
  k_ev<32><<<512, 256, 0, stream>>>(v0, g1_evW, g1_evb, evA);
  k_edge_g1<<<2048, 256, 0, stream>>>(in_e, g1_eW, g1_eb, evA, e_ws,
                                      v0, (const uint4*)g1_vWp, g1_vb,
                                      (const uint4*)evWp, inn_evb, vA, evB);

  // ---- inner layers (v ping-pong: l even reads vA->vB, l odd reads vB->vA) ----
  float* vbufs[2] = {vA, vB};
  for (int l = 0; l < 4; ++l) {
    float* vin_l  = vbufs[l & 1];
    float* vout_l = vbufs[(l + 1) & 1];
    if (l == 0)
      k_edge_inner<false, false><<<2048, 256, 0, stream>>>(e_ws, Wt,
          inn_eb, evB, g3_eW, edt, vin_l, vout_l,
          (const uint4*)vWp, inn_vb, stats,
          nullptr, nullptr, nullptr, nullptr, nullptr);
    else if (l < 3)
      k_edge_inner<false, true><<<2048, 256, 0, stream>>>(e_ws, Wt + l * 16384,
          inn_eb + l * 128, evB, g3_eW, edt, vin_l, vout_l,
          (const uint4*)vWp + l * 4096, inn_vb + l * 128, stats + l * 128,
          stats + (l - 1) * 128, bn_g + (l - 1) * 64, bn_b + (l - 1) * 64,
          evWtB + l * 16384, inn_evb + l * 128);
    else
      k_edge_inner<true, true><<<2048, 256, 0, stream>>>(e_ws, Wt + l * 16384,
          inn_eb + l * 128, evB, g3_eW, edt, vin_l, vout_l,
          (const uint4*)vWp + l * 4096, inn_vb + l * 128, stats + l * 128,
          stats + (l - 1) * 128, bn_g + (l - 1) * 64, bn_b + (l - 1) * 64,
          evWtB + l * 16384, inn_evb + l * 128);
  }

  // ---- g3 final (v after l=3 lands in vA) ----
  k_g3<<<64, 256, 0, stream>>>(vA, stats + 384, bn_g + 192, bn_b + 192,
                               g3_evW, g3_evb, g3_eb, edt, g3_vW, g3_vb,
                               out_v, out_e);
}